// Round 1
// baseline (648.098 us; speedup 1.0000x reference)
//
#include <hip/hip_runtime.h>
#include <math.h>

typedef __attribute__((ext_vector_type(4))) float f32x4;
typedef __attribute__((ext_vector_type(8))) short bf16x8;

__device__ inline short f2bf(float f) {
    union { float f; unsigned u; } v; v.f = f;
    unsigned u = v.u;
    u += 0x7fffu + ((u >> 16) & 1u);   // RNE
    return (short)(u >> 16);
}

// ---------------- avgpool + sinusoidal bias init ----------------
__global__ __launch_bounds__(256) void k_avg_init(const float* __restrict__ x,
                                                  float* __restrict__ altx,
                                                  float* __restrict__ bias0) {
    int blk = blockIdx.x, t = threadIdx.x;
    if (blk < 512) {
        int wv = t >> 6, lane = t & 63;
        int p = blk * 4 + wv;              // p = c2*64 + c1
        const float* row = x + (size_t)p * 2048;
        int c2 = p >> 6, c1 = p & 63;
        int m = c1 * 32 + c2;
        for (int seg = 0; seg < 32; ++seg) {
            float v = row[seg * 64 + lane];
            for (int off = 32; off; off >>= 1) v += __shfl_xor(v, off, 64);
            if (lane == 0) altx[seg * 2048 + m] = v * (1.0f / 64.0f);
        }
    } else {
        int i = blk - 512;
        const float kln = logf(10000.0f) / 1024.0f;
        for (int l = t; l < 2048; l += 256) {
            int c = l & ~1;
            float ang = (float)i * expf(-(float)c * kln);
            bias0[i * 2048 + l] = (l & 1) ? cosf(ang) : sinf(ang);
        }
    }
}

// ---------------- skinny GEMM v4: full-KR register accumulation, NO atomics ----------------
// grid = (N/64, K/KR).  Block stages A[32][KR] in LDS once (single barrier),
// streams B with 2-deep register prefetch, writes partial sums to part[split][32][N].
template<int KR>
__global__ __launch_bounds__(256, 3) void k_gemm(const float* __restrict__ W,
                                                 const float* __restrict__ act,
                                                 float* __restrict__ part,
                                                 int N, int K) {
    constexpr int NKC = KR / 128;
    __shared__ short lAs[32][KR + 8];
    int t = threadIdx.x;
    int lane = t & 63, wv = t >> 6;
    int m = lane & 15, q = lane >> 4;
    int nb = blockIdx.x * 64 + wv * 16;
    size_t kbeg = (size_t)blockIdx.y * KR;

    // --- A stage: thread covers row t>>3, APT cols at (t&7)*APT ---
    constexpr int APT = KR / 8;
    int arow = t >> 3, acol = (t & 7) * APT;
    const float* ap = act + (size_t)arow * K + kbeg + acol;
    float4 areg[APT / 4];
    #pragma unroll
    for (int j = 0; j < APT / 4; ++j) areg[j] = *(const float4*)(ap + j * 4);
    #pragma unroll
    for (int j = 0; j < APT / 4; ++j) {
        short4 c = { f2bf(areg[j].x), f2bf(areg[j].y), f2bf(areg[j].z), f2bf(areg[j].w) };
        *(short4*)&lAs[arow][acol + j * 4] = c;
    }

    // --- B prefetch for kc=0 (overlaps the barrier) ---
    const float* B = W + (size_t)(nb + m) * K + kbeg + q * 8;
    float4 Bb[2][8];
    #pragma unroll
    for (int s = 0; s < 4; ++s) {
        Bb[0][2 * s]     = *(const float4*)(B + s * 32);
        Bb[0][2 * s + 1] = *(const float4*)(B + s * 32 + 4);
    }
    __syncthreads();

    f32x4 acc0 = {0.f, 0.f, 0.f, 0.f};
    f32x4 acc1 = {0.f, 0.f, 0.f, 0.f};
    #pragma unroll
    for (int kc = 0; kc < NKC; ++kc) {
        const int cur = kc & 1;
        if (kc + 1 < NKC) {
            const float* Bn = B + (kc + 1) * 128;
            #pragma unroll
            for (int s = 0; s < 4; ++s) {
                Bb[cur ^ 1][2 * s]     = *(const float4*)(Bn + s * 32);
                Bb[cur ^ 1][2 * s + 1] = *(const float4*)(Bn + s * 32 + 4);
            }
        }
        #pragma unroll
        for (int s = 0; s < 4; ++s) {
            bf16x8 fa0 = *(const bf16x8*)&lAs[m][kc * 128 + s * 32 + q * 8];
            bf16x8 fa1 = *(const bf16x8*)&lAs[m + 16][kc * 128 + s * 32 + q * 8];
            float4 bl = Bb[cur][2 * s], bh = Bb[cur][2 * s + 1];
            bf16x8 fb = { f2bf(bl.x), f2bf(bl.y), f2bf(bl.z), f2bf(bl.w),
                          f2bf(bh.x), f2bf(bh.y), f2bf(bh.z), f2bf(bh.w) };
            acc0 = __builtin_amdgcn_mfma_f32_16x16x32_bf16(fa0, fb, acc0, 0, 0, 0);
            acc1 = __builtin_amdgcn_mfma_f32_16x16x32_bf16(fa1, fb, acc1, 0, 0, 0);
        }
    }

    // C/D layout: col = lane&15 (n), row = q*4+reg (token).  Plain stores (no atomics).
    float* op = part + (size_t)blockIdx.y * 32 * N + (size_t)(q * 4) * N + nb + m;
    #pragma unroll
    for (int r = 0; r < 4; ++r) {
        op[(size_t)r * N] = acc0[r];
        op[(size_t)(r + 16) * N] = acc1[r];
    }
}

// ---------------- prep1: s = sum(partials)+base; y = LN1(s).  FINAL: just store s ----------------
template<bool FINAL>
__global__ __launch_bounds__(256) void k_prep1(const float* __restrict__ part, int nsplit,
                                               const float* __restrict__ base2d,
                                               const float* __restrict__ bias1d,
                                               const float* __restrict__ g,
                                               const float* __restrict__ b,
                                               float* __restrict__ sres,
                                               float* __restrict__ y) {
    int row = blockIdx.x, t = threadIdx.x;
    float v[8];
    const float* p0 = part + row * 2048;
    #pragma unroll
    for (int j = 0; j < 8; ++j) {
        int col = j * 256 + t;
        float acc = base2d ? base2d[row * 2048 + col] : bias1d[col];
        const float* p = p0 + col;
        for (int s = 0; s < nsplit; ++s) acc += p[(size_t)s * 65536];
        v[j] = acc;
    }
    float* sr = sres + row * 2048;
    if (FINAL) {
        #pragma unroll
        for (int j = 0; j < 8; ++j) sr[j * 256 + t] = v[j];
        return;
    }
    float sm = 0.f, ss = 0.f;
    #pragma unroll
    for (int j = 0; j < 8; ++j) { sm += v[j]; ss += v[j] * v[j]; }
    for (int off = 32; off; off >>= 1) { sm += __shfl_xor(sm, off, 64); ss += __shfl_xor(ss, off, 64); }
    __shared__ float as[4], bs[4];
    int wv = t >> 6, lane = t & 63;
    if (lane == 0) { as[wv] = sm; bs[wv] = ss; }
    __syncthreads();
    sm = as[0] + as[1] + as[2] + as[3];
    ss = bs[0] + bs[1] + bs[2] + bs[3];
    float mu = sm * (1.0f / 2048.0f);
    float rstd = rsqrtf(ss * (1.0f / 2048.0f) - mu * mu + 1e-5f);
    float* yr = y + row * 2048;
    #pragma unroll
    for (int j = 0; j < 8; ++j) {
        int col = j * 256 + t;
        sr[col] = v[j];
        yr[col] = (v[j] - mu) * rstd * g[col] + b[col];
    }
}

// ---------------- prep2: v = s + sum(part2); s = LN2(v)+v ----------------
__global__ __launch_bounds__(256) void k_prep2(const float* __restrict__ part,
                                               const float* __restrict__ sin_,
                                               const float* __restrict__ g,
                                               const float* __restrict__ b,
                                               float* __restrict__ sout) {
    int row = blockIdx.x, t = threadIdx.x;
    float v[8];
    const float* p0 = part + row * 2048;
    #pragma unroll
    for (int j = 0; j < 8; ++j) {
        int col = j * 256 + t;
        float acc = sin_[row * 2048 + col];
        const float* p = p0 + col;
        #pragma unroll
        for (int s = 0; s < 8; ++s) acc += p[(size_t)s * 65536];
        v[j] = acc;
    }
    float sm = 0.f, ss = 0.f;
    #pragma unroll
    for (int j = 0; j < 8; ++j) { sm += v[j]; ss += v[j] * v[j]; }
    for (int off = 32; off; off >>= 1) { sm += __shfl_xor(sm, off, 64); ss += __shfl_xor(ss, off, 64); }
    __shared__ float as[4], bs[4];
    int wv = t >> 6, lane = t & 63;
    if (lane == 0) { as[wv] = sm; bs[wv] = ss; }
    __syncthreads();
    sm = as[0] + as[1] + as[2] + as[3];
    ss = bs[0] + bs[1] + bs[2] + bs[3];
    float mu = sm * (1.0f / 2048.0f);
    float rstd = rsqrtf(ss * (1.0f / 2048.0f) - mu * mu + 1e-5f);
    float* sr = sout + row * 2048;
    #pragma unroll
    for (int j = 0; j < 8; ++j) {
        int col = j * 256 + t;
        sr[col] = (v[j] - mu) * rstd * g[col] + b[col] + v[j];
    }
}

// ---------------- scan: reduce qkv partials, per-head scalar attn + serial cumsum ----------------
__global__ __launch_bounds__(256) void k_scan(const float* __restrict__ part,  // [8][32][6144]
                                              float* __restrict__ imv) {
    int h = blockIdx.x, t = threadIdx.x;
    __shared__ float vq[32][129], vk[32][129], vv[32][129];
    __shared__ float rsa[32];
    #pragma unroll
    for (int kk = 0; kk < 16; ++kk) {
        int flat = kk * 256 + t;           // 0..4095
        int i = flat >> 7, d = flat & 127;
        const float* p = part + (size_t)i * 6144 + h * 128 + d;
        float aq = 0.f, ak = 0.f, av = 0.f;
        #pragma unroll
        for (int s = 0; s < 8; ++s) {
            const float* ps = p + (size_t)s * 196608;
            aq += ps[0]; ak += ps[2048]; av += ps[4096];
        }
        vq[i][d] = aq; vk[i][d] = ak; vv[i][d] = av;
    }
    __syncthreads();
    {
        int i = t >> 3, sub = t & 7;
        float acc = 0.f;
        #pragma unroll
        for (int dd = 0; dd < 16; ++dd) {
            int d = sub * 16 + dd;
            acc += vq[i][d] * vk[i][d];
        }
        acc += __shfl_xor(acc, 1, 64);
        acc += __shfl_xor(acc, 2, 64);
        acc += __shfl_xor(acc, 4, 64);
        if (sub == 0) rsa[i] = acc * 0.08838834764831845f;   // 1/sqrt(128)
    }
    __syncthreads();
    if (t < 128) {
        float acc = 0.f;
        #pragma unroll
        for (int i = 0; i < 32; ++i) {
            acc += rsa[i] * vv[i][t];
            imv[i * 2048 + h * 128 + t] = acc;
        }
    }
}

// ---------------- act: h = gelu(sum(part3) + fc1_b) ----------------
__global__ __launch_bounds__(256) void k_act(const float* __restrict__ part,  // [4][32][8192]
                                             const float* __restrict__ fc1_b,
                                             float* __restrict__ h) {
    int idx0 = blockIdx.x * 2048 + threadIdx.x;
    #pragma unroll
    for (int j = 0; j < 8; ++j) {
        int idx = idx0 + j * 256;
        float v = fc1_b[idx & 8191];
        #pragma unroll
        for (int s = 0; s < 4; ++s) v += part[(size_t)s * 262144 + idx];
        h[idx] = 0.5f * v * (1.0f + erff(v * 0.70710678118654752f));
    }
}

extern "C" void kernel_launch(void* const* d_in, const int* in_sizes, int n_in,
                              void* d_out, int out_size, void* d_ws, size_t ws_size,
                              hipStream_t stream) {
    const float* x      = (const float*)d_in[0];
    const float* weight = (const float*)d_in[1];
    const float* Wqkv   = (const float*)d_in[2];
    const float* Wo     = (const float*)d_in[3];
    const float* ln1_g  = (const float*)d_in[4];
    const float* ln1_b  = (const float*)d_in[5];
    const float* ln2_g  = (const float*)d_in[6];
    const float* ln2_b  = (const float*)d_in[7];
    const float* fc1_w  = (const float*)d_in[8];
    const float* fc1_b  = (const float*)d_in[9];
    const float* fc2_w  = (const float*)d_in[10];
    const float* fc2_b  = (const float*)d_in[11];
    float* ws    = (float*)d_ws;
    float* altx  = ws;                   // 65536
    float* bias0 = ws + 65536;           // 65536
    float* sres  = ws + 131072;          // 65536
    float* y     = ws + 196608;          // 65536
    float* imv   = ws + 262144;          // 65536
    float* h     = ws + 327680;          // 262144
    float* part2 = ws + 589824;          // 8*65536 = 524288
    float* pool  = ws + 1114112;         // max(8*196608, 4*262144, 16*65536) = 1572864
    float* outF  = (float*)d_out;

    k_avg_init<<<544, 256, 0, stream>>>(x, altx, bias0);
    // s partials = weight @ altx   (8 splits of K=2048)
    k_gemm<256><<<dim3(32, 8), 256, 0, stream>>>(weight, altx, pool, 2048, 2048);
    for (int a = 0; a < 3; ++a) {
        // s = sum(partials) + (sinusoidal | fc2_b); y = LN1(s)
        k_prep1<false><<<32, 256, 0, stream>>>(pool, a ? 16 : 8,
                                               a ? nullptr : bias0,
                                               a ? fc2_b : nullptr,
                                               ln1_g, ln1_b, sres, y);
        // qkv partials (8 splits)
        k_gemm<256><<<dim3(96, 8), 256, 0, stream>>>(Wqkv + (size_t)a * 12582912, y, pool, 6144, 2048);
        k_scan<<<16, 256, 0, stream>>>(pool, imv);
        // Wo partials (8 splits)
        k_gemm<256><<<dim3(32, 8), 256, 0, stream>>>(Wo + (size_t)a * 4194304, imv, part2, 2048, 2048);
        // v = s + sum(part2); s = LN2(v)+v  (in-place on sres)
        k_prep2<<<32, 256, 0, stream>>>(part2, sres, ln2_g, ln2_b, sres);
        // fc1 partials (4 splits of K=2048, KR=512)
        k_gemm<512><<<dim3(128, 4), 256, 0, stream>>>(fc1_w, sres, pool, 8192, 2048);
        k_act<<<128, 256, 0, stream>>>(pool, fc1_b, h);
        // fc2 partials (16 splits of K=8192, KR=512)
        k_gemm<512><<<dim3(32, 16), 256, 0, stream>>>(fc2_w, h, pool, 2048, 8192);
    }
    // final: out = sum(fc2 partials) + fc2_b
    k_prep1<true><<<32, 256, 0, stream>>>(pool, 16, nullptr, fc2_b,
                                          nullptr, nullptr, outF, nullptr);
}